// Round 1
// baseline (348.461 us; speedup 1.0000x reference)
//
#include <hip/hip_runtime.h>

typedef __bf16 bf16_t;
typedef __bf16 bf16x2 __attribute__((ext_vector_type(2)));
typedef __bf16 bf16x4 __attribute__((ext_vector_type(4)));
typedef __bf16 bf16x8 __attribute__((ext_vector_type(8)));
typedef float f32x4 __attribute__((ext_vector_type(4)));

#define S_LEN 2048
#define BSZ 4
#define NHEAD 16
#define HDIM 64
#define RDIM 1024
#define QKV_N 3072
#define NTOK 8192

// ---------------- async global->LDS (16B per lane, linear dest) ----------------
__device__ static inline void gload_lds16(const void* g, void* l) {
    __builtin_amdgcn_global_load_lds(
        (const __attribute__((address_space(1))) void*)(unsigned long long)g,
        (__attribute__((address_space(3))) void*)(unsigned long long)l,
        16, 0, 0);
}

// ---------------- LayerNorm: fp32 [8192][1024] -> bf16 xn ----------------
__global__ __launch_bounds__(256) void ln_kernel(const float* __restrict__ x,
                                                 const float* __restrict__ lw,
                                                 const float* __restrict__ lb,
                                                 bf16_t* __restrict__ xn) {
    int row = blockIdx.x;
    int tid = threadIdx.x;
    const float4* xr = (const float4*)(x + (size_t)row * RDIM);
    float4 v = xr[tid];
    float s  = v.x + v.y + v.z + v.w;
    float ss = v.x*v.x + v.y*v.y + v.z*v.z + v.w*v.w;
#pragma unroll
    for (int off = 1; off < 64; off <<= 1) {
        s  += __shfl_xor(s, off, 64);
        ss += __shfl_xor(ss, off, 64);
    }
    __shared__ float red[8];
    int wid = tid >> 6, lane = tid & 63;
    if (lane == 0) { red[wid] = s; red[wid + 4] = ss; }
    __syncthreads();
    float S  = red[0] + red[1] + red[2] + red[3];
    float SS = red[4] + red[5] + red[6] + red[7];
    float mu  = S * (1.f / RDIM);
    float var = SS * (1.f / RDIM) - mu * mu;
    float rsig = rsqrtf(var + 1e-5f);
    float4 wv = ((const float4*)lw)[tid];
    float4 bv = ((const float4*)lb)[tid];
    bf16x4 o;
    o[0] = (bf16_t)((v.x - mu) * rsig * wv.x + bv.x);
    o[1] = (bf16_t)((v.y - mu) * rsig * wv.y + bv.y);
    o[2] = (bf16_t)((v.z - mu) * rsig * wv.z + bv.z);
    o[3] = (bf16_t)((v.w - mu) * rsig * wv.w + bv.w);
    *(bf16x4*)(xn + (size_t)row * RDIM + tid * 4) = o;
}

// ---------------- fp32 -> bf16 convert (weights) ----------------
__global__ __launch_bounds__(256) void cvt_kernel(const float* __restrict__ src,
                                                  bf16_t* __restrict__ dst, int n4) {
    int i = blockIdx.x * 256 + threadIdx.x;
    if (i < n4) {
        float4 v = ((const float4*)src)[i];
        bf16x4 o;
        o[0] = (bf16_t)v.x; o[1] = (bf16_t)v.y; o[2] = (bf16_t)v.z; o[3] = (bf16_t)v.w;
        ((bf16x4*)dst)[i] = o;
    }
}

// ---------------- GEMM C = A @ B^T  (A [M][1024] bf16, B [N][1024] bf16) -------
// 128x128 tile, BK=32, 4 waves (2x2), 16x16x32 bf16 MFMA, global_load_lds staging.
// MODE 0: C -> bf16 (ldc stride). MODE 1: C = acc + X (fp32), fp32 out.
template <int MODE>
__global__ __launch_bounds__(256) void gemm_bt_kernel(const bf16_t* __restrict__ A,
                                                      const bf16_t* __restrict__ Bm,
                                                      bf16_t* __restrict__ Cb,
                                                      const float* __restrict__ X,
                                                      float* __restrict__ Cf,
                                                      int ldc) {
    const int K = 1024;
    __shared__ bf16_t As[128 * 32];
    __shared__ bf16_t Bs[128 * 32];
    int tid = threadIdx.x;
    int lane = tid & 63, wid = tid >> 6;
    int l15 = lane & 15, lg = lane >> 4;
    int wm = wid >> 1, wn = wid & 1;
    int row0 = blockIdx.y * 128;
    int col0 = blockIdx.x * 128;

    int sr = tid >> 2;            // 0..63
    int sc = (tid & 3) * 8;       // 0,8,16,24
    const bf16_t* aSrc = A + (size_t)(row0 + sr) * K + sc;
    const bf16_t* bSrc = Bm + (size_t)(col0 + sr) * K + sc;
    bf16_t* aDst = As + tid * 8;
    bf16_t* bDst = Bs + tid * 8;

    f32x4 acc[4][4] = {};
    for (int kt = 0; kt < K; kt += 32) {
        gload_lds16(aSrc + kt, aDst);
        gload_lds16(aSrc + kt + (size_t)64 * K, aDst + 2048);
        gload_lds16(bSrc + kt, bDst);
        gload_lds16(bSrc + kt + (size_t)64 * K, bDst + 2048);
        __syncthreads();
        bf16x8 a[4], b[4];
#pragma unroll
        for (int m = 0; m < 4; m++)
            a[m] = *(const bf16x8*)(As + (wm * 64 + m * 16 + l15) * 32 + lg * 8);
#pragma unroll
        for (int n = 0; n < 4; n++)
            b[n] = *(const bf16x8*)(Bs + (wn * 64 + n * 16 + l15) * 32 + lg * 8);
#pragma unroll
        for (int m = 0; m < 4; m++)
#pragma unroll
            for (int n = 0; n < 4; n++)
                acc[m][n] = __builtin_amdgcn_mfma_f32_16x16x32_bf16(a[m], b[n], acc[m][n], 0, 0, 0);
        __syncthreads();
    }

    int crow = row0 + wm * 64 + lg * 4;
    int ccol = col0 + wn * 64 + l15;
#pragma unroll
    for (int m = 0; m < 4; m++) {
#pragma unroll
        for (int n = 0; n < 4; n++) {
#pragma unroll
            for (int r = 0; r < 4; r++) {
                int rr = crow + m * 16 + r;
                int cc = ccol + n * 16;
                size_t idx = (size_t)rr * ldc + cc;
                if (MODE == 0) {
                    Cb[idx] = (bf16_t)acc[m][n][r];
                } else {
                    Cf[idx] = acc[m][n][r] + X[idx];
                }
            }
        }
    }
}

// ---------------- Flash attention ----------------
// grid (32 qblocks, 4 batch, 16 heads), 256 threads = 4 waves, 16 queries/wave.
// qkv layout: [token=s*4+b][3072] bf16, per (b,h): q at h*192, k at +64, v at +128.
// Swapped QK^T: S^T frag (m=key, n=query=l15). P via per-wave LDS. O^T accumulate.
__global__ __launch_bounds__(256) void attn_kernel(const bf16_t* __restrict__ qkv,
                                                   bf16_t* __restrict__ aout) {
    __shared__ bf16_t Ks[64 * 72];       // K tile, row-major [key][d], stride 72
    __shared__ bf16_t VTs[64 * 72];      // V^T tile [d][key], stride 72
    __shared__ bf16_t Ps[4][16 * 72];    // per-wave P [query][key], stride 72
    int tid = threadIdx.x;
    int lane = tid & 63, wid = tid >> 6;
    int l15 = lane & 15, lg = lane >> 4;
    int b = blockIdx.y, h = blockIdx.z;
    int sq = blockIdx.x * 64 + wid * 16 + l15;

    const bf16_t* qbase = qkv + (size_t)(sq * 4 + b) * QKV_N + h * 192;
    bf16x8 qf0 = *(const bf16x8*)(qbase + lg * 8);
    bf16x8 qf1 = *(const bf16x8*)(qbase + 32 + lg * 8);

    float mrun = -3e38f, lrun = 0.f;
    f32x4 o[4] = {};
    const float scale = 0.03125f;  // 1/sqrt(1024)

    int krow = tid >> 2;            // 0..63
    int kcol = (tid & 3) * 16;      // 0,16,32,48
    int vr0 = (tid & 31) * 2;       // 0..62
    int vc0 = (tid >> 5) * 8;       // 0..56

    for (int kv0 = 0; kv0 < S_LEN; kv0 += 64) {
        __syncthreads();
        {
            const bf16_t* ksrc = qkv + (size_t)((kv0 + krow) * 4 + b) * QKV_N + h * 192 + 64 + kcol;
            bf16x8 k0 = *(const bf16x8*)ksrc;
            bf16x8 k1 = *(const bf16x8*)(ksrc + 8);
            const bf16_t* vsrc = qkv + (size_t)((kv0 + vr0) * 4 + b) * QKV_N + h * 192 + 128 + vc0;
            bf16x8 v0 = *(const bf16x8*)vsrc;
            bf16x8 v1 = *(const bf16x8*)(vsrc + 4 * QKV_N);
            *(bf16x8*)(Ks + krow * 72 + kcol) = k0;
            *(bf16x8*)(Ks + krow * 72 + kcol + 8) = k1;
#pragma unroll
            for (int i = 0; i < 8; i++) {
                bf16x2 pr; pr[0] = v0[i]; pr[1] = v1[i];
                *(bf16x2*)(VTs + (vc0 + i) * 72 + vr0) = pr;
            }
        }
        __syncthreads();

        // QK^T (swapped): s[kb] = K[16 keys] . Q^T  -> D[m=key][n=query]
        f32x4 sc4[4];
#pragma unroll
        for (int kb = 0; kb < 4; kb++) {
            bf16x8 ka = *(const bf16x8*)(Ks + (kb * 16 + l15) * 72 + lg * 8);
            bf16x8 kc = *(const bf16x8*)(Ks + (kb * 16 + l15) * 72 + 32 + lg * 8);
            f32x4 z = {0.f, 0.f, 0.f, 0.f};
            z = __builtin_amdgcn_mfma_f32_16x16x32_bf16(ka, qf0, z, 0, 0, 0);
            z = __builtin_amdgcn_mfma_f32_16x16x32_bf16(kc, qf1, z, 0, 0, 0);
            sc4[kb] = z;
        }

        // online softmax over keys for query l15 (keys spread over lg x reg x kb)
        float tmax = -3e38f;
#pragma unroll
        for (int kb = 0; kb < 4; kb++)
#pragma unroll
            for (int r = 0; r < 4; r++) tmax = fmaxf(tmax, sc4[kb][r]);
        tmax = fmaxf(tmax, __shfl_xor(tmax, 16, 64));
        tmax = fmaxf(tmax, __shfl_xor(tmax, 32, 64));
        float mnew = fmaxf(mrun, tmax * scale);
        float corr = __expf(mrun - mnew);
        float lsum = 0.f;
#pragma unroll
        for (int kb = 0; kb < 4; kb++) {
            float p0 = __expf(sc4[kb][0] * scale - mnew);
            float p1 = __expf(sc4[kb][1] * scale - mnew);
            float p2 = __expf(sc4[kb][2] * scale - mnew);
            float p3 = __expf(sc4[kb][3] * scale - mnew);
            lsum += (p0 + p1) + (p2 + p3);
            bf16x2 q01; q01[0] = (bf16_t)p0; q01[1] = (bf16_t)p1;
            bf16x2 q23; q23[0] = (bf16_t)p2; q23[1] = (bf16_t)p3;
            *(bf16x2*)(&Ps[wid][l15 * 72 + kb * 16 + lg * 4]) = q01;
            *(bf16x2*)(&Ps[wid][l15 * 72 + kb * 16 + lg * 4 + 2]) = q23;
        }
        lsum += __shfl_xor(lsum, 16, 64);
        lsum += __shfl_xor(lsum, 32, 64);
        lrun = lrun * corr + lsum;
        mrun = mnew;
#pragma unroll
        for (int dc = 0; dc < 4; dc++) {
            o[dc][0] *= corr; o[dc][1] *= corr; o[dc][2] *= corr; o[dc][3] *= corr;
        }

        // PV: O^T[d][q] += V^T[d][key] * P^T[key][q]
#pragma unroll
        for (int kc = 0; kc < 2; kc++) {
            bf16x8 pf = *(const bf16x8*)(&Ps[wid][l15 * 72 + kc * 32 + lg * 8]);
#pragma unroll
            for (int dc = 0; dc < 4; dc++) {
                bf16x8 vf = *(const bf16x8*)(VTs + (dc * 16 + l15) * 72 + kc * 32 + lg * 8);
                o[dc] = __builtin_amdgcn_mfma_f32_16x16x32_bf16(vf, pf, o[dc], 0, 0, 0);
            }
        }
    }

    float linv = 1.f / lrun;
    bf16_t* ob = aout + (size_t)(sq * 4 + b) * RDIM + h * 64 + lg * 4;
#pragma unroll
    for (int dc = 0; dc < 4; dc++) {
        bf16x4 ov;
        ov[0] = (bf16_t)(o[dc][0] * linv);
        ov[1] = (bf16_t)(o[dc][1] * linv);
        ov[2] = (bf16_t)(o[dc][2] * linv);
        ov[3] = (bf16_t)(o[dc][3] * linv);
        *(bf16x4*)(ob + dc * 16) = ov;
    }
}

// ---------------- host launch ----------------
extern "C" void kernel_launch(void* const* d_in, const int* in_sizes, int n_in,
                              void* d_out, int out_size, void* d_ws, size_t ws_size,
                              hipStream_t stream) {
    (void)in_sizes; (void)n_in; (void)out_size; (void)ws_size;
    const float* x     = (const float*)d_in[0];
    const float* w_qkv = (const float*)d_in[1];
    const float* w_out = (const float*)d_in[2];
    const float* ln_w  = (const float*)d_in[3];
    const float* ln_b  = (const float*)d_in[4];
    float* out = (float*)d_out;
    char* ws = (char*)d_ws;

    bf16_t* xn      = (bf16_t*)(ws);                 // 8192*1024*2 = 16,777,216
    bf16_t* wqkv_bf = (bf16_t*)(ws + 16777216);      // 3072*1024*2 =  6,291,456
    bf16_t* wout_bf = (bf16_t*)(ws + 23068672);      // 1024*1024*2 =  2,097,152
    bf16_t* qkvb    = (bf16_t*)(ws + 25165824);      // 8192*3072*2 = 50,331,648
    bf16_t* attn    = xn;  // xn is dead after QKV GEMM; reuse for attention output

    ln_kernel<<<NTOK, 256, 0, stream>>>(x, ln_w, ln_b, xn);
    cvt_kernel<<<3072, 256, 0, stream>>>(w_qkv, wqkv_bf, (QKV_N * RDIM) / 4);
    cvt_kernel<<<1024, 256, 0, stream>>>(w_out, wout_bf, (RDIM * RDIM) / 4);

    gemm_bt_kernel<0><<<dim3(QKV_N / 128, NTOK / 128), 256, 0, stream>>>(
        xn, wqkv_bf, qkvb, nullptr, nullptr, QKV_N);

    attn_kernel<<<dim3(S_LEN / 64, BSZ, NHEAD), 256, 0, stream>>>(qkvb, attn);

    gemm_bt_kernel<1><<<dim3(RDIM / 128, NTOK / 128), 256, 0, stream>>>(
        attn, wout_bf, nullptr, x, out, RDIM);
}

// Round 5
// 328.998 us; speedup vs baseline: 1.0592x; 1.0592x over previous
//
#include <hip/hip_runtime.h>

typedef __bf16 bf16_t;
typedef __bf16 bf16x2 __attribute__((ext_vector_type(2)));
typedef __bf16 bf16x4 __attribute__((ext_vector_type(4)));
typedef __bf16 bf16x8 __attribute__((ext_vector_type(8)));
typedef float f32x4 __attribute__((ext_vector_type(4)));

#define S_LEN 2048
#define BSZ 4
#define NHEAD 16
#define HDIM 64
#define RDIM 1024
#define QKV_N 3072
#define NTOK 8192

// ---------------- async global->LDS (16B per lane, linear dest) ----------------
__device__ static inline void gload_lds16(const void* g, void* l) {
    __builtin_amdgcn_global_load_lds(
        (const __attribute__((address_space(1))) void*)(unsigned long long)g,
        (__attribute__((address_space(3))) void*)(unsigned long long)l,
        16, 0, 0);
}

// ---------------- LayerNorm: fp32 [8192][1024] -> bf16 xn ----------------
__global__ __launch_bounds__(256) void ln_kernel(const float* __restrict__ x,
                                                 const float* __restrict__ lw,
                                                 const float* __restrict__ lb,
                                                 bf16_t* __restrict__ xn) {
    int row = blockIdx.x;
    int tid = threadIdx.x;
    const float4* xr = (const float4*)(x + (size_t)row * RDIM);
    float4 v = xr[tid];
    float s  = v.x + v.y + v.z + v.w;
    float ss = v.x*v.x + v.y*v.y + v.z*v.z + v.w*v.w;
#pragma unroll
    for (int off = 1; off < 64; off <<= 1) {
        s  += __shfl_xor(s, off, 64);
        ss += __shfl_xor(ss, off, 64);
    }
    __shared__ float red[8];
    int wid = tid >> 6, lane = tid & 63;
    if (lane == 0) { red[wid] = s; red[wid + 4] = ss; }
    __syncthreads();
    float S  = red[0] + red[1] + red[2] + red[3];
    float SS = red[4] + red[5] + red[6] + red[7];
    float mu  = S * (1.f / RDIM);
    float var = SS * (1.f / RDIM) - mu * mu;
    float rsig = rsqrtf(var + 1e-5f);
    float4 wv = ((const float4*)lw)[tid];
    float4 bv = ((const float4*)lb)[tid];
    bf16x4 o;
    o[0] = (bf16_t)((v.x - mu) * rsig * wv.x + bv.x);
    o[1] = (bf16_t)((v.y - mu) * rsig * wv.y + bv.y);
    o[2] = (bf16_t)((v.z - mu) * rsig * wv.z + bv.z);
    o[3] = (bf16_t)((v.w - mu) * rsig * wv.w + bv.w);
    *(bf16x4*)(xn + (size_t)row * RDIM + tid * 4) = o;
}

// ---------------- fp32 -> bf16 convert (weights) ----------------
__global__ __launch_bounds__(256) void cvt_kernel(const float* __restrict__ src,
                                                  bf16_t* __restrict__ dst, int n4) {
    int i = blockIdx.x * 256 + threadIdx.x;
    if (i < n4) {
        float4 v = ((const float4*)src)[i];
        bf16x4 o;
        o[0] = (bf16_t)v.x; o[1] = (bf16_t)v.y; o[2] = (bf16_t)v.z; o[3] = (bf16_t)v.w;
        ((bf16x4*)dst)[i] = o;
    }
}

// ---------------- GEMM C = A @ B^T  (A [M][1024] bf16, B [N][1024] bf16) -------
template <int MODE>
__global__ __launch_bounds__(256) void gemm_bt_kernel(const bf16_t* __restrict__ A,
                                                      const bf16_t* __restrict__ Bm,
                                                      bf16_t* __restrict__ Cb,
                                                      const float* __restrict__ X,
                                                      float* __restrict__ Cf,
                                                      int ldc) {
    const int K = 1024;
    __shared__ bf16_t As[128 * 32];
    __shared__ bf16_t Bs[128 * 32];
    int tid = threadIdx.x;
    int lane = tid & 63, wid = tid >> 6;
    int l15 = lane & 15, lg = lane >> 4;
    int wm = wid >> 1, wn = wid & 1;
    int row0 = blockIdx.y * 128;
    int col0 = blockIdx.x * 128;

    int sr = tid >> 2;
    int sc = (tid & 3) * 8;
    const bf16_t* aSrc = A + (size_t)(row0 + sr) * K + sc;
    const bf16_t* bSrc = Bm + (size_t)(col0 + sr) * K + sc;
    bf16_t* aDst = As + tid * 8;
    bf16_t* bDst = Bs + tid * 8;

    f32x4 acc[4][4] = {};
    for (int kt = 0; kt < K; kt += 32) {
        gload_lds16(aSrc + kt, aDst);
        gload_lds16(aSrc + kt + (size_t)64 * K, aDst + 2048);
        gload_lds16(bSrc + kt, bDst);
        gload_lds16(bSrc + kt + (size_t)64 * K, bDst + 2048);
        __syncthreads();
        bf16x8 a[4], b[4];
#pragma unroll
        for (int m = 0; m < 4; m++)
            a[m] = *(const bf16x8*)(As + (wm * 64 + m * 16 + l15) * 32 + lg * 8);
#pragma unroll
        for (int n = 0; n < 4; n++)
            b[n] = *(const bf16x8*)(Bs + (wn * 64 + n * 16 + l15) * 32 + lg * 8);
#pragma unroll
        for (int m = 0; m < 4; m++)
#pragma unroll
            for (int n = 0; n < 4; n++)
                acc[m][n] = __builtin_amdgcn_mfma_f32_16x16x32_bf16(a[m], b[n], acc[m][n], 0, 0, 0);
        __syncthreads();
    }

    int crow = row0 + wm * 64 + lg * 4;
    int ccol = col0 + wn * 64 + l15;
#pragma unroll
    for (int m = 0; m < 4; m++) {
#pragma unroll
        for (int n = 0; n < 4; n++) {
#pragma unroll
            for (int r = 0; r < 4; r++) {
                int rr = crow + m * 16 + r;
                int cc = ccol + n * 16;
                size_t idx = (size_t)rr * ldc + cc;
                if (MODE == 0) {
                    Cb[idx] = (bf16_t)acc[m][n][r];
                } else {
                    Cf[idx] = acc[m][n][r] + X[idx];
                }
            }
        }
    }
}

// ---------------- Flash attention (pipelined, swizzled K, R1-style V^T) -------
// grid (32 qblocks, 4 batch, 16 heads), 256 threads = 4 waves, 16 queries/wave.
// K LDS: [key][64] 16B chunks XOR-swizzled by key&7 (gload_lds, src-swizzled).
// V LDS: V^T [d][key] stride 72, built via VALU transpose (R1-proven), read as
//        plain bf16x8 (bisect: replaces R3/R4's ds_read_b64_tr_b16 path).
// P LDS: per-wave [16][88]. Softmax: R1-exact.
__global__ __launch_bounds__(256) void attn_kernel(const bf16_t* __restrict__ qkv,
                                                   bf16_t* __restrict__ aout) {
    __shared__ __align__(16) bf16_t Kb[2][4096];
    __shared__ __align__(16) bf16_t VTb[2][64 * 72];
    __shared__ __align__(16) bf16_t Ps[4][16 * 88];
    int tid = threadIdx.x;
    int lane = tid & 63, wid = tid >> 6;
    int l15 = lane & 15, lg = lane >> 4;
    int b = blockIdx.y, h = blockIdx.z;
    int sq = blockIdx.x * 64 + wid * 16 + l15;

    const float scale = 0.03125f;  // 1/sqrt(1024)

    const bf16_t* qbase = qkv + (size_t)(sq * 4 + b) * QKV_N + h * 192;
    bf16x8 qf0 = *(const bf16x8*)(qbase + lg * 8);
    bf16x8 qf1 = *(const bf16x8*)(qbase + 32 + lg * 8);

    // ---- staging lane decode (loop-invariant) ----
    int kKeyOff = lane >> 3;
    int kChunk  = (lane & 7) ^ (lane >> 3);
    int vr0 = (tid & 31) * 2;       // key pair base 0..62
    int vc0 = (tid >> 5) * 8;       // d octet 0..56

    int sw = l15 & 7;
    int koA = ((lg ^ sw)) * 8;
    int koC = (((lg + 4) ^ sw)) * 8;

    float mrun = -3e38f, lrun = 0.f;
    f32x4 o[4] = {};

    // ---- prologue: stage tile 0 into buf 0 ----
    {
        const bf16_t* ks = qkv + (size_t)(((0 + wid * 16 + kKeyOff) * 4 + b)) * QKV_N + h * 192 + 64 + kChunk * 8;
        bf16_t* kd = &Kb[0][wid * 1024 + lane * 8];
        gload_lds16(ks, kd);
        gload_lds16(ks + (size_t)8 * 4 * QKV_N, kd + 512);
        const bf16_t* vs = qkv + (size_t)((0 + vr0) * 4 + b) * QKV_N + h * 192 + 128 + vc0;
        bf16x8 v0 = *(const bf16x8*)vs;
        bf16x8 v1 = *(const bf16x8*)(vs + (size_t)4 * QKV_N);
#pragma unroll
        for (int i = 0; i < 8; i++) {
            bf16x2 pr; pr[0] = v0[i]; pr[1] = v1[i];
            *(bf16x2*)(&VTb[0][(vc0 + i) * 72 + vr0]) = pr;
        }
    }
    __syncthreads();

    int cur = 0;
    for (int t = 0; t < S_LEN / 64; t++) {
        // ---- stage tile t+1 into buf cur^1 (K via DMA; V loads early) ----
        bf16x8 v0, v1;
        bool do_stage = (t + 1) < (S_LEN / 64);
        if (do_stage) {
            int kv0 = (t + 1) * 64;
            const bf16_t* ks = qkv + (size_t)(((kv0 + wid * 16 + kKeyOff) * 4 + b)) * QKV_N + h * 192 + 64 + kChunk * 8;
            bf16_t* kd = &Kb[cur ^ 1][wid * 1024 + lane * 8];
            gload_lds16(ks, kd);
            gload_lds16(ks + (size_t)8 * 4 * QKV_N, kd + 512);
            const bf16_t* vs = qkv + (size_t)((kv0 + vr0) * 4 + b) * QKV_N + h * 192 + 128 + vc0;
            v0 = *(const bf16x8*)vs;
            v1 = *(const bf16x8*)(vs + (size_t)4 * QKV_N);
        }

        // ---- QK^T (swapped): sc4[kb] = K-rows . Q-rows ----
        const bf16_t* kbase = &Kb[cur][l15 * 64];
        bf16x8 kfA[4], kfC[4];
#pragma unroll
        for (int kb = 0; kb < 4; kb++) {
            kfA[kb] = *(const bf16x8*)(kbase + kb * 1024 + koA);
            kfC[kb] = *(const bf16x8*)(kbase + kb * 1024 + koC);
        }
        f32x4 sc4[4];
        __builtin_amdgcn_s_setprio(1);
#pragma unroll
        for (int kb = 0; kb < 4; kb++) {
            f32x4 z = {0.f, 0.f, 0.f, 0.f};
            z = __builtin_amdgcn_mfma_f32_16x16x32_bf16(kfA[kb], qf0, z, 0, 0, 0);
            z = __builtin_amdgcn_mfma_f32_16x16x32_bf16(kfC[kb], qf1, z, 0, 0, 0);
            sc4[kb] = z;
        }
        __builtin_amdgcn_s_setprio(0);

        // ---- online softmax, R1-exact (scaled m, always update, P <= 1) ----
        float tmax = sc4[0][0];
#pragma unroll
        for (int kb = 0; kb < 4; kb++)
#pragma unroll
            for (int r = 0; r < 4; r++) tmax = fmaxf(tmax, sc4[kb][r]);
        tmax = fmaxf(tmax, __shfl_xor(tmax, 16, 64));
        tmax = fmaxf(tmax, __shfl_xor(tmax, 32, 64));
        float mnew = fmaxf(mrun, tmax * scale);
        float corr = __expf(mrun - mnew);
        float lsum = 0.f;
#pragma unroll
        for (int kb = 0; kb < 4; kb++) {
            float p0 = __expf(sc4[kb][0] * scale - mnew);
            float p1 = __expf(sc4[kb][1] * scale - mnew);
            float p2 = __expf(sc4[kb][2] * scale - mnew);
            float p3 = __expf(sc4[kb][3] * scale - mnew);
            lsum += (p0 + p1) + (p2 + p3);
            bf16x4 pw;
            pw[0] = (bf16_t)p0; pw[1] = (bf16_t)p1; pw[2] = (bf16_t)p2; pw[3] = (bf16_t)p3;
            *(bf16x4*)(&Ps[wid][l15 * 88 + kb * 16 + lg * 4]) = pw;
        }
        lsum += __shfl_xor(lsum, 16, 64);
        lsum += __shfl_xor(lsum, 32, 64);
        lrun = lrun * corr + lsum;
        mrun = mnew;
#pragma unroll
        for (int dc = 0; dc < 4; dc++) {
            o[dc][0] *= corr; o[dc][1] *= corr; o[dc][2] *= corr; o[dc][3] *= corr;
        }

        // ---- deferred V^T LDS writes (transpose; global loads have landed) ----
        if (do_stage) {
#pragma unroll
            for (int i = 0; i < 8; i++) {
                bf16x2 pr; pr[0] = v0[i]; pr[1] = v1[i];
                *(bf16x2*)(&VTb[cur ^ 1][(vc0 + i) * 72 + vr0]) = pr;
            }
        }

        // ---- PV: O^T[d][q] += V^T[d][k] * P[q][k] ----
#pragma unroll
        for (int kc = 0; kc < 2; kc++) {
            bf16x8 pf = *(const bf16x8*)(&Ps[wid][l15 * 88 + kc * 32 + lg * 8]);
            __builtin_amdgcn_s_setprio(1);
#pragma unroll
            for (int dc = 0; dc < 4; dc++) {
                bf16x8 vf = *(const bf16x8*)(&VTb[cur][(dc * 16 + l15) * 72 + kc * 32 + lg * 8]);
                o[dc] = __builtin_amdgcn_mfma_f32_16x16x32_bf16(vf, pf, o[dc], 0, 0, 0);
            }
            __builtin_amdgcn_s_setprio(0);
        }

        __syncthreads();
        cur ^= 1;
    }

    float linv = 1.f / lrun;
    bf16_t* ob = aout + (size_t)(sq * 4 + b) * RDIM + h * 64 + lg * 4;
#pragma unroll
    for (int dc = 0; dc < 4; dc++) {
        bf16x4 ov;
        ov[0] = (bf16_t)(o[dc][0] * linv);
        ov[1] = (bf16_t)(o[dc][1] * linv);
        ov[2] = (bf16_t)(o[dc][2] * linv);
        ov[3] = (bf16_t)(o[dc][3] * linv);
        *(bf16x4*)(ob + dc * 16) = ov;
    }
}

// ---------------- host launch ----------------
extern "C" void kernel_launch(void* const* d_in, const int* in_sizes, int n_in,
                              void* d_out, int out_size, void* d_ws, size_t ws_size,
                              hipStream_t stream) {
    (void)in_sizes; (void)n_in; (void)out_size; (void)ws_size;
    const float* x     = (const float*)d_in[0];
    const float* w_qkv = (const float*)d_in[1];
    const float* w_out = (const float*)d_in[2];
    const float* ln_w  = (const float*)d_in[3];
    const float* ln_b  = (const float*)d_in[4];
    float* out = (float*)d_out;
    char* ws = (char*)d_ws;

    bf16_t* xn      = (bf16_t*)(ws);                 // 8192*1024*2 = 16,777,216
    bf16_t* wqkv_bf = (bf16_t*)(ws + 16777216);      // 3072*1024*2 =  6,291,456
    bf16_t* wout_bf = (bf16_t*)(ws + 23068672);      // 1024*1024*2 =  2,097,152
    bf16_t* qkvb    = (bf16_t*)(ws + 25165824);      // 8192*3072*2 = 50,331,648
    bf16_t* attn    = xn;  // xn dead after QKV GEMM

    ln_kernel<<<NTOK, 256, 0, stream>>>(x, ln_w, ln_b, xn);
    cvt_kernel<<<3072, 256, 0, stream>>>(w_qkv, wqkv_bf, (QKV_N * RDIM) / 4);
    cvt_kernel<<<1024, 256, 0, stream>>>(w_out, wout_bf, (RDIM * RDIM) / 4);

    gemm_bt_kernel<0><<<dim3(QKV_N / 128, NTOK / 128), 256, 0, stream>>>(
        xn, wqkv_bf, qkvb, nullptr, nullptr, QKV_N);

    attn_kernel<<<dim3(S_LEN / 64, BSZ, NHEAD), 256, 0, stream>>>(qkvb, attn);

    gemm_bt_kernel<1><<<dim3(RDIM / 128, NTOK / 128), 256, 0, stream>>>(
        attn, wout_bf, nullptr, x, out, RDIM);
}